// Round 18
// baseline (93.820 us; speedup 1.0000x reference)
//
#include <hip/hip_runtime.h>
#include <hip/hip_bf16.h>

typedef __attribute__((ext_vector_type(4))) float          f32x4;
typedef __attribute__((ext_vector_type(4))) int            i32x4;
typedef __attribute__((ext_vector_type(2))) unsigned int   u32x2;
typedef __attribute__((ext_vector_type(4))) unsigned int   u32x4;
typedef __attribute__((ext_vector_type(8))) unsigned short u16x8;

#define Cc 512
#define Vv 512
#define BM 128
#define NTILE 1250

#define BOUND 0.04419417382415922f           /* 1/sqrt(512) — torch Linear init bound */
#define INV_SW (127.0f / BOUND)
#define OSCALE (BOUND / 16129.0f)            /* BOUND / (127*127) */

// W2i: i8 W in 16x16x64-MFMA B-fragment order.
// (v,k) -> frag (v>>4)*8 + (k>>6); lane (v&15)+16*((k>>4)&3); byte k&15
__device__ unsigned g_W2i[Vv * Cc / 4];      // uint array -> 16B-aligned
// bf16 tanh tables (L2-resident per XCD)
__device__ unsigned short g_ta[1600 * Cc];
__device__ unsigned short g_tp[400 * Cc];

__device__ __forceinline__ float fast_tanh(float x) {
    float e = __expf(2.0f * x);
    return 1.0f - 2.0f * __builtin_amdgcn_rcpf(e + 1.0f);
}

__device__ __forceinline__ unsigned cvt_pk_bf16(float lo, float hi) {
    unsigned r;
    asm("v_cvt_pk_bf16_f32 %0, %1, %2" : "=v"(r) : "v"(lo), "v"(hi));
    return r;
}

__device__ __forceinline__ float bf2f(unsigned short b) {
    return __uint_as_float(((unsigned)b) << 16);
}

__device__ __forceinline__ unsigned pack4(int q0, int q1, int q2, int q3) {
    return (q0 & 0xff) | ((q1 & 0xff) << 8) | ((q2 & 0xff) << 16) | (q3 << 24);
}

// blocks [0,64) -> W2i quant+swizzle; [64,464) -> tanh(enc) bf16; [464,564) -> tanh(pred) bf16
__global__ __launch_bounds__(256) void prep_kernel(
    const float* __restrict__ W, const float* __restrict__ enc,
    const float* __restrict__ pred)
{
    const int b = blockIdx.x;
    if (b < 64) {
        int gid = b * 256 + threadIdx.x;     // 0..16383, 16 k-elems each
        int v  = gid >> 5;
        int k0 = (gid & 31) * 16;
        const float* wp = W + v * Cc + k0;
        f32x4 wv[4];
#pragma unroll
        for (int c = 0; c < 4; ++c) wv[c] = *(const f32x4*)(wp + c * 4);
        u32x4 o;
#pragma unroll
        for (int c = 0; c < 4; ++c)
            o[c] = pack4(__float2int_rn(wv[c][0] * INV_SW),
                         __float2int_rn(wv[c][1] * INV_SW),
                         __float2int_rn(wv[c][2] * INV_SW),
                         __float2int_rn(wv[c][3] * INV_SW));
        int f  = (v >> 4) * 8 + (k0 >> 6);
        int ln = (v & 15) + 16 * ((k0 >> 4) & 3);
        *(u32x4*)((char*)g_W2i + f * 1024 + ln * 16) = o;
    } else if (b < 464) {
        int gid = (b - 64) * 256 + threadIdx.x;     // 8 elems each
        f32x4 a = *(const f32x4*)(enc + gid * 8);
        f32x4 c = *(const f32x4*)(enc + gid * 8 + 4);
        u32x4 o;
        o[0] = cvt_pk_bf16(fast_tanh(a[0]), fast_tanh(a[1]));
        o[1] = cvt_pk_bf16(fast_tanh(a[2]), fast_tanh(a[3]));
        o[2] = cvt_pk_bf16(fast_tanh(c[0]), fast_tanh(c[1]));
        o[3] = cvt_pk_bf16(fast_tanh(c[2]), fast_tanh(c[3]));
        *(u32x4*)(g_ta + gid * 8) = o;
    } else {
        int gid = (b - 464) * 256 + threadIdx.x;
        f32x4 a = *(const f32x4*)(pred + gid * 8);
        f32x4 c = *(const f32x4*)(pred + gid * 8 + 4);
        u32x4 o;
        o[0] = cvt_pk_bf16(fast_tanh(a[0]), fast_tanh(a[1]));
        o[1] = cvt_pk_bf16(fast_tanh(a[2]), fast_tanh(a[3]));
        o[2] = cvt_pk_bf16(fast_tanh(c[0]), fast_tanh(c[1]));
        o[3] = cvt_pk_bf16(fast_tanh(c[2]), fast_tanh(c[3]));
        *(u32x4*)(g_tp + gid * 8) = o;
    }
}

// BM=128, 512 thr, 8 waves: wave (wm,wn) = (w>>2, w&3) owns 64 rows x 128 cols.
// i8 tile = 64 KB LDS -> still 2 blocks/CU (champion occupancy) with HALF the
// per-row B-traffic; wm pairs share W2i fragments (L1 hits). V processed in 4
// quarters of 32 cols with mid-stores (R17-validated drain spreading).
__global__ __launch_bounds__(512, 4) void joiner_main(
    const float* __restrict__ bias,  // (512,)
    float* __restrict__ out)         // (160000, 512)
{
    __shared__ unsigned char As[BM * Cc];    // 64 KB i8 tile, XOR-swizzled rows

    const int tid = threadIdx.x;

    // ---- bijective XCD-chunked tile remap (8 XCDs, 1250 tiles; q=156,r=2) ----
    const int xcd  = blockIdx.x & 7;
    const int idx  = blockIdx.x >> 3;
    const int tile = (xcd < 2 ? xcd * 157 : 2 * 157 + (xcd - 2) * 156) + idx;

    // ---- stage: A = q127(tanh-sum(ta,tp)) from bf16 tables -> i8 LDS ----
    {
        const int r = tid >> 2;          // 0..127 (tile row)
        const int q = tid & 3;           // k-interleave slot
        const int m  = tile * BM + r;
        const int et = m / 100;
        const int u  = m - et * 100;
        const int bb = m / 40000;
        const int pr = bb * 100 + u;
        const unsigned short* taP = g_ta + et * Cc;
        const unsigned short* tpP = g_tp + pr * Cc;
        char* asB = (char*)As;
        const int swz = (r & 7) << 4;
#pragma unroll
        for (int c = 0; c < 16; ++c) {
            const int k0 = q * 8 + c * 32;      // interleaved chunks: bank-spread
            u16x8 ta8 = *(const u16x8*)(taP + k0);
            u16x8 tp8 = *(const u16x8*)(tpP + k0);
            int qq[8];
#pragma unroll
            for (int j = 0; j < 8; ++j) {
                float a = bf2f(ta8[j]);
                float p = bf2f(tp8[j]);
                float n = (a + p) *
                          __builtin_amdgcn_rcpf(__builtin_fmaf(a, p, 1.0f));
                qq[j] = __float2int_rn(n * 127.0f);
            }
            u32x2 o;
            o[0] = pack4(qq[0], qq[1], qq[2], qq[3]);
            o[1] = pack4(qq[4], qq[5], qq[6], qq[7]);
            int byte = r * 512 + k0;            // i8: 1 byte per elem
            *(u32x2*)(asB + (byte ^ swz)) = o;
        }
    }

    // ---- compute setup ----
    const int lane = tid & 63;
    const int w    = tid >> 6;
    const int wm   = w >> 2;            // row half (0,1)
    const int wn   = w & 3;             // col group of 128
    const int lc   = lane & 15;
    const int lkB  = (lane >> 4) << 4;  // k-byte offset within 64-k step
    const int lr   = (lane >> 4) << 2;

    // W2i window for this wave's 128 cols: v-groups wn*8 + jg (jg = qt*2 + jj);
    // frag(jg, ks) at wb + ((jg*8 + ks) << 10). wm=0/1 read identical frags.
    const char* wb = (const char*)g_W2i + (size_t)wn * 65536 + lane * 16;
    const char* asB = (const char*)As;
    const int aswz = (lc & 7) << 4;
    const int rowB = (wm * 64 + lc) * 512;   // LDS byte base of this lane's rows

    i32x4 bcur[2], bnx[2];
#pragma unroll
    for (int jj = 0; jj < 2; ++jj)
        bcur[jj] = *(const i32x4*)(wb + ((jj * 8 + 0) << 10));

    __syncthreads();   // only barrier

#pragma unroll
    for (int qt = 0; qt < 4; ++qt) {
        i32x4 acc[4][2];
#pragma unroll
        for (int i = 0; i < 4; ++i) { acc[i][0] = (i32x4){0,0,0,0}; acc[i][1] = (i32x4){0,0,0,0}; }

#pragma unroll 2
        for (int ks = 0; ks < 8; ++ks) {
            if (ks < 7) {
#pragma unroll
                for (int jj = 0; jj < 2; ++jj)
                    bnx[jj] = *(const i32x4*)(wb + (((qt * 2 + jj) * 8 + ks + 1) << 10));
            }
            i32x4 af[4];
#pragma unroll
            for (int i = 0; i < 4; ++i) {
                int byte = rowB + i * 16 * 512 + ks * 64 + lkB;
                af[i] = *(const i32x4*)(asB + (byte ^ aswz));
            }
#pragma unroll
            for (int i = 0; i < 4; ++i)
#pragma unroll
                for (int jj = 0; jj < 2; ++jj)
                    acc[i][jj] = __builtin_amdgcn_mfma_i32_16x16x64_i8(
                        af[i], bcur[jj], acc[i][jj], 0, 0, 0);
#pragma unroll
            for (int jj = 0; jj < 2; ++jj) bcur[jj] = bnx[jj];
        }

        // prime next quarter's first fragments BEFORE the stores (in-order vmcnt)
        if (qt < 3) {
#pragma unroll
            for (int jj = 0; jj < 2; ++jj)
                bcur[jj] = *(const i32x4*)(wb + ((((qt + 1) * 2 + jj) * 8 + 0) << 10));
        }

        // ---- quarter epilogue: stores spread across the block's lifetime ----
        {
            const int cb = wn * 128 + qt * 32;
            float b0 = bias[cb + lc];
            float b1 = bias[cb + 16 + lc];
#pragma unroll
            for (int i = 0; i < 4; ++i) {
#pragma unroll
                for (int q4 = 0; q4 < 4; ++q4) {
                    size_t row = (size_t)(tile * BM + wm * 64 + i * 16 + lr + q4);
                    float* op = out + row * Vv + cb;
                    __builtin_nontemporal_store(
                        __builtin_fmaf((float)acc[i][0][q4], OSCALE, b0), op + lc);
                    __builtin_nontemporal_store(
                        __builtin_fmaf((float)acc[i][1][q4], OSCALE, b1), op + 16 + lc);
                }
            }
        }
    }
}

extern "C" void kernel_launch(void* const* d_in, const int* in_sizes, int n_in,
                              void* d_out, int out_size, void* d_ws, size_t ws_size,
                              hipStream_t stream) {
    const float* enc  = (const float*)d_in[0];
    const float* pred = (const float*)d_in[1];
    const float* W    = (const float*)d_in[2];
    const float* bias = (const float*)d_in[3];
    float* out        = (float*)d_out;

    prep_kernel<<<564, 256, 0, stream>>>(W, enc, pred);
    joiner_main<<<NTILE, 512, 0, stream>>>(bias, out);
}

// Round 19
// 90.075 us; speedup vs baseline: 1.0416x; 1.0416x over previous
//
#include <hip/hip_runtime.h>
#include <hip/hip_bf16.h>

typedef __attribute__((ext_vector_type(4)))  float          f32x4;
typedef __attribute__((ext_vector_type(4)))  int            i32x4;
typedef __attribute__((ext_vector_type(16))) int            i32x16;
typedef __attribute__((ext_vector_type(2)))  unsigned int   u32x2;
typedef __attribute__((ext_vector_type(4)))  unsigned int   u32x4;
typedef __attribute__((ext_vector_type(8)))  unsigned short u16x8;

#define Cc 512
#define Vv 512
#define BM 64
#define NTILE 2500

#define BOUND 0.04419417382415922f           /* 1/sqrt(512) — torch Linear init bound */
#define INV_SW (127.0f / BOUND)
#define OSCALE (BOUND / 16129.0f)            /* BOUND / (127*127) */

// W2i: i8 W in 32x32x32-MFMA B-fragment order.
// (v,k) -> frag (v>>5)*16 + (k>>5); lane (v&31) + 32*((k>>4)&1); byte k&15
__device__ unsigned g_W2i[Vv * Cc / 4];      // uint array -> 16B-aligned
// bf16 tanh tables (L2-resident per XCD)
__device__ unsigned short g_ta[1600 * Cc];
__device__ unsigned short g_tp[400 * Cc];

__device__ __forceinline__ float fast_tanh(float x) {
    float e = __expf(2.0f * x);
    return 1.0f - 2.0f * __builtin_amdgcn_rcpf(e + 1.0f);
}

__device__ __forceinline__ unsigned cvt_pk_bf16(float lo, float hi) {
    unsigned r;
    asm("v_cvt_pk_bf16_f32 %0, %1, %2" : "=v"(r) : "v"(lo), "v"(hi));
    return r;
}

__device__ __forceinline__ float bf2f(unsigned short b) {
    return __uint_as_float(((unsigned)b) << 16);
}

__device__ __forceinline__ unsigned pack4(int q0, int q1, int q2, int q3) {
    return (q0 & 0xff) | ((q1 & 0xff) << 8) | ((q2 & 0xff) << 16) | (q3 << 24);
}

// blocks [0,64) -> W2i quant+swizzle (32x32 frag order);
// [64,464) -> tanh(enc) bf16; [464,564) -> tanh(pred) bf16
__global__ __launch_bounds__(256) void prep_kernel(
    const float* __restrict__ W, const float* __restrict__ enc,
    const float* __restrict__ pred)
{
    const int b = blockIdx.x;
    if (b < 64) {
        int gid = b * 256 + threadIdx.x;     // 0..16383, 16 k-elems each
        int v  = gid >> 5;
        int k0 = (gid & 31) * 16;
        const float* wp = W + v * Cc + k0;
        f32x4 wv[4];
#pragma unroll
        for (int c = 0; c < 4; ++c) wv[c] = *(const f32x4*)(wp + c * 4);
        u32x4 o;
#pragma unroll
        for (int c = 0; c < 4; ++c)
            o[c] = pack4(__float2int_rn(wv[c][0] * INV_SW),
                         __float2int_rn(wv[c][1] * INV_SW),
                         __float2int_rn(wv[c][2] * INV_SW),
                         __float2int_rn(wv[c][3] * INV_SW));
        int f  = (v >> 5) * 16 + (k0 >> 5);
        int ln = (v & 31) + 32 * ((k0 >> 4) & 1);
        *(u32x4*)((char*)g_W2i + f * 1024 + ln * 16) = o;
    } else if (b < 464) {
        int gid = (b - 64) * 256 + threadIdx.x;     // 8 elems each
        f32x4 a = *(const f32x4*)(enc + gid * 8);
        f32x4 c = *(const f32x4*)(enc + gid * 8 + 4);
        u32x4 o;
        o[0] = cvt_pk_bf16(fast_tanh(a[0]), fast_tanh(a[1]));
        o[1] = cvt_pk_bf16(fast_tanh(a[2]), fast_tanh(a[3]));
        o[2] = cvt_pk_bf16(fast_tanh(c[0]), fast_tanh(c[1]));
        o[3] = cvt_pk_bf16(fast_tanh(c[2]), fast_tanh(c[3]));
        *(u32x4*)(g_ta + gid * 8) = o;
    } else {
        int gid = (b - 464) * 256 + threadIdx.x;
        f32x4 a = *(const f32x4*)(pred + gid * 8);
        f32x4 c = *(const f32x4*)(pred + gid * 8 + 4);
        u32x4 o;
        o[0] = cvt_pk_bf16(fast_tanh(a[0]), fast_tanh(a[1]));
        o[1] = cvt_pk_bf16(fast_tanh(a[2]), fast_tanh(a[3]));
        o[2] = cvt_pk_bf16(fast_tanh(c[0]), fast_tanh(c[1]));
        o[3] = cvt_pk_bf16(fast_tanh(c[2]), fast_tanh(c[3]));
        *(u32x4*)(g_tp + gid * 8) = o;
    }
}

__global__ __launch_bounds__(512, 4) void joiner_main(
    const float* __restrict__ bias,  // (512,)
    float* __restrict__ out)         // (160000, 512)
{
    __shared__ unsigned char As[BM * Cc];    // 32 KB i8 tile, XOR-swizzled rows

    const int tid = threadIdx.x;

    // ---- bijective XCD-chunked tile remap (8 XCDs, 2500 tiles; q=312,r=4) ----
    const int xcd  = blockIdx.x & 7;
    const int idx  = blockIdx.x >> 3;
    const int tile = (xcd < 4 ? xcd * 313 : 4 * 313 + (xcd - 4) * 312) + idx;

    // ---- stage: A = q127(tanh-sum(ta,tp)) from bf16 tables -> i8 LDS ----
    // swizzle (r&15)<<4: 2-way banks for the 32-lane row span of 32x32 A-frag reads
    {
        const int r = tid >> 3;          // 0..63 (tile row)
        const int q = tid & 7;           // k-interleave slot
        const int m  = tile * BM + r;
        const int et = m / 100;
        const int u  = m - et * 100;
        const int bb = m / 40000;
        const int pr = bb * 100 + u;
        const unsigned short* taP = g_ta + et * Cc;
        const unsigned short* tpP = g_tp + pr * Cc;
        char* asB = (char*)As;
        const int swz = (r & 15) << 4;
#pragma unroll
        for (int c = 0; c < 8; ++c) {
            const int k0 = q * 8 + c * 64;      // interleaved chunks: bank-spread
            u16x8 ta8 = *(const u16x8*)(taP + k0);
            u16x8 tp8 = *(const u16x8*)(tpP + k0);
            int qq[8];
#pragma unroll
            for (int j = 0; j < 8; ++j) {
                float a = bf2f(ta8[j]);
                float p = bf2f(tp8[j]);
                float n = (a + p) *
                          __builtin_amdgcn_rcpf(__builtin_fmaf(a, p, 1.0f));
                qq[j] = __float2int_rn(n * 127.0f);
            }
            u32x2 o;
            o[0] = pack4(qq[0], qq[1], qq[2], qq[3]);
            o[1] = pack4(qq[4], qq[5], qq[6], qq[7]);
            int byte = r * 512 + k0;            // i8: 1 byte per elem
            *(u32x2*)(asB + (byte ^ swz)) = o;
        }
    }

    // ---- compute setup ----
    const int lane = tid & 63;
    const int w    = tid >> 6;          // wave -> V slice [w*64, (w+1)*64)
    const int lrow = lane & 31;         // A-row / B-col within 32-block
    const int lkh  = lane >> 5;         // k-half selector (16B)

    // B-fragment stream: frag (w*2 + jj)*16 + ks2, 1KB each
    const char* wb = (const char*)g_W2i + (size_t)(w * 2) * 16 * 1024 + lane * 16;
    const char* asB = (const char*)As;

    i32x4 bcur, bnx;
    bcur = *(const i32x4*)(wb + 0);     // frag(jj=0, ks2=0), primed pre-barrier

    __syncthreads();   // only barrier

    // A-frag addresses: row = i*32 + lrow; byte = row*512 + ks2*32 + lkh*16
    const int rowA0 = lrow;             // i = 0
    const int rowA1 = 32 + lrow;        // i = 1
    const int abyte0 = rowA0 * 512 + lkh * 16;
    const int abyte1 = rowA1 * 512 + lkh * 16;
    const int aswz0 = (rowA0 & 15) << 4;
    const int aswz1 = (rowA1 & 15) << 4;

    const int colBase = w * 64 + lrow;

#pragma unroll
    for (int jj = 0; jj < 2; ++jj) {
        i32x16 acc0 = (i32x16)(0), acc1 = (i32x16)(0);

#pragma unroll 4
        for (int ks2 = 0; ks2 < 16; ++ks2) {
            if (ks2 < 15)
                bnx = *(const i32x4*)(wb + ((jj * 16 + ks2 + 1) << 10));
            i32x4 a0 = *(const i32x4*)(asB + ((abyte0 + ks2 * 32) ^ aswz0));
            i32x4 a1 = *(const i32x4*)(asB + ((abyte1 + ks2 * 32) ^ aswz1));
            acc0 = __builtin_amdgcn_mfma_i32_32x32x32_i8(a0, bcur, acc0, 0, 0, 0);
            acc1 = __builtin_amdgcn_mfma_i32_32x32x32_i8(a1, bcur, acc1, 0, 0, 0);
            bcur = bnx;
        }

        // prime next half's first fragment BEFORE the stores (in-order vmcnt)
        if (jj == 0)
            bcur = *(const i32x4*)(wb + ((16 + 0) << 10));

        // ---- half epilogue: full-line stores ----
        // C/D: col = lane&31, row = (q&3) + 8*(q>>2) + 4*(lane>>5)
        // per store instr: 2 rows x 32 lanes x 4B = 2 full 128B lines
        {
            const float bia = bias[colBase + jj * 32];
            float* opb = out + (size_t)tile * BM * Vv + w * 64 + jj * 32 + lrow;
#pragma unroll
            for (int q4 = 0; q4 < 16; ++q4) {
                int r0 = (q4 & 3) + 8 * (q4 >> 2) + 4 * lkh;
                __builtin_nontemporal_store(
                    __builtin_fmaf((float)acc0[q4], OSCALE, bia),
                    opb + (size_t)r0 * Vv);
                __builtin_nontemporal_store(
                    __builtin_fmaf((float)acc1[q4], OSCALE, bia),
                    opb + (size_t)(32 + r0) * Vv);
            }
        }
    }
}

extern "C" void kernel_launch(void* const* d_in, const int* in_sizes, int n_in,
                              void* d_out, int out_size, void* d_ws, size_t ws_size,
                              hipStream_t stream) {
    const float* enc  = (const float*)d_in[0];
    const float* pred = (const float*)d_in[1];
    const float* W    = (const float*)d_in[2];
    const float* bias = (const float*)d_in[3];
    float* out        = (float*)d_out;

    prep_kernel<<<564, 256, 0, stream>>>(W, enc, pred);
    joiner_main<<<NTILE, 512, 0, stream>>>(bias, out);
}